// Round 2
// baseline (222.340 us; speedup 1.0000x reference)
//
#include <hip/hip_runtime.h>
#include <cstdint>
#include <cstddef>

#define HH 512
#define WW 512
#define BB 64
#define ROWS_PER_BLOCK 16

// ws layout:
//   bits   : uint64_t [2][BB][HH][8]   (bit j of word w = boundary at col w*64+j)  = 4 MB
//   counter: unsigned long long                                                    = 8 B
//
// Algebra: for binary masks the class-0 and class-1 boundaries are identical
// (maxpool(1-m)-minpool(1-m) == maxpool(m)-minpool(m)), so boundary_mask = 2*b'
// with b' in {0,1}, and loss = 4/N * popcount(bp' XOR bg') — exact in integers.
// -inf maxpool padding == window restriction: handled by row-bounds skip
// (vertical) and index clamp (horizontal; duplication is harmless for max/min).

__global__ __launch_bounds__(512) void boundary_bits_kernel(
    const float* __restrict__ seg, const float* __restrict__ gt,
    uint64_t* __restrict__ bits,
    unsigned long long* __restrict__ counter)
{
    if (blockIdx.x == 0 && blockIdx.y == 0 && blockIdx.z == 0 && threadIdx.x == 0)
        *counter = 0ull;

    const int chunk = blockIdx.x;   // row chunks of ROWS_PER_BLOCK
    const int batch = blockIdx.y;   // 0..63
    const int z     = blockIdx.z;   // 0 = seg, 1 = gt
    const float* src = (z == 0 ? seg : gt) + (size_t)batch * HH * WW;
    const int tid = threadIdx.x;    // column index 0..511

    __shared__ float rowbuf[ROWS_PER_BLOCK + 2][WW];

    const int r0 = chunk * ROWS_PER_BLOCK;
    #pragma unroll
    for (int rr = 0; rr < ROWS_PER_BLOCK + 2; ++rr) {
        int g = r0 - 1 + rr;
        rowbuf[rr][tid] = (unsigned(g) < HH) ? src[(size_t)g * WW + tid] : 0.0f;
    }
    __syncthreads();

    const int jm1 = tid > 0 ? tid - 1 : 0;
    const int jp1 = tid < WW - 1 ? tid + 1 : WW - 1;

    uint64_t* bbase = bits + (((size_t)z * BB + batch) * HH + r0) * 8;

    for (int q = 0; q < ROWS_PER_BLOCK; ++q) {
        const int i = r0 + q;
        float wmax = -1e30f, wmin = 1e30f;
        #pragma unroll
        for (int dr = -1; dr <= 1; ++dr) {
            int g = i + dr;
            if (unsigned(g) < HH) {
                int l = q + 1 + dr;
                float a = rowbuf[l][jm1];
                float c = rowbuf[l][tid];
                float d = rowbuf[l][jp1];
                wmax = fmaxf(wmax, fmaxf(fmaxf(a, c), d));
                wmin = fminf(wmin, fminf(fminf(a, c), d));
            }
        }
        bool pred = (wmax - wmin) > 0.5f;   // boundary pixel (values are exactly 0/1)
        unsigned long long m = __ballot(pred);
        if ((tid & 63) == 0) {
            bbase[q * 8 + (tid >> 6)] = m;
        }
    }
}

__global__ __launch_bounds__(512) void mask_xor_kernel(
    const uint64_t* __restrict__ bits,
    unsigned long long* __restrict__ counter)
{
    const int batch = blockIdx.x;
    const int tid = threadIdx.x;
    const int wave = tid >> 6, lane = tid & 63;

    __shared__ uint64_t colmask[2][8];
    __shared__ unsigned char rowhit[2][HH];
    __shared__ int red[8];

    for (int z = 0; z < 2; ++z) {
        const uint64_t* bb = bits + ((size_t)z * BB + batch) * HH * 8;
        // row sums: thread tid owns row tid (popcount of its 8 words)
        int rs = 0;
        #pragma unroll
        for (int w = 0; w < 8; ++w) rs += __popcll(bb[(size_t)tid * 8 + w]);
        rowhit[z][tid] = (rs >= 300) ? 1 : 0;
        __syncthreads();
        // column sums over non-hit rows; thread tid owns column tid
        int cnt = 0;
        for (int i = 0; i < HH; ++i) {
            if (!rowhit[z][i]) {                 // uniform branch per block
                uint64_t w = bb[i * 8 + wave];   // broadcast within wave
                cnt += (int)((w >> lane) & 1ull);
            }
        }
        bool keep = (cnt < 300);                 // column survives
        unsigned long long m = __ballot(keep);
        if (lane == 0) colmask[z][wave] = m;
        __syncthreads();
    }

    // XOR-popcount of masked boundaries; thread tid owns row tid (8 words)
    const uint64_t* bp = bits + ((size_t)0 * BB + batch) * HH * 8;
    const uint64_t* bg = bits + ((size_t)1 * BB + batch) * HH * 8;
    const bool hp = rowhit[0][tid] != 0;
    const bool hg = rowhit[1][tid] != 0;
    int cnt = 0;
    #pragma unroll
    for (int w = 0; w < 8; ++w) {
        uint64_t wp = hp ? 0ull : (bp[(size_t)tid * 8 + w] & colmask[0][w]);
        uint64_t wg = hg ? 0ull : (bg[(size_t)tid * 8 + w] & colmask[1][w]);
        cnt += __popcll(wp ^ wg);
    }
    // block reduce
    for (int off = 32; off; off >>= 1) cnt += __shfl_down(cnt, off, 64);
    if (lane == 0) red[wave] = cnt;
    __syncthreads();
    if (tid == 0) {
        int s = 0;
        #pragma unroll
        for (int w2 = 0; w2 < 8; ++w2) s += red[w2];
        atomicAdd(counter, (unsigned long long)s);
    }
}

__global__ void finalize_kernel(const unsigned long long* __restrict__ counter,
                                float* __restrict__ out)
{
    if (threadIdx.x == 0 && blockIdx.x == 0) {
        double v = (double)(*counter) * (4.0 / 16777216.0);  // 4/N, N = 64*512*512
        out[0] = (float)v;
    }
}

extern "C" void kernel_launch(void* const* d_in, const int* in_sizes, int n_in,
                              void* d_out, int out_size, void* d_ws, size_t ws_size,
                              hipStream_t stream) {
    const float* seg = (const float*)d_in[0];
    const float* gt  = (const float*)d_in[1];
    float* out = (float*)d_out;

    uint8_t* ws = (uint8_t*)d_ws;
    const size_t bits_bytes = (size_t)2 * BB * HH * 8 * sizeof(uint64_t);   // 4 MB
    uint64_t* bits = (uint64_t*)ws;
    unsigned long long* counter = (unsigned long long*)(ws + bits_bytes);

    dim3 g1(HH / ROWS_PER_BLOCK, BB, 2);
    boundary_bits_kernel<<<g1, 512, 0, stream>>>(seg, gt, bits, counter);
    mask_xor_kernel<<<BB, 512, 0, stream>>>(bits, counter);
    finalize_kernel<<<1, 1, 0, stream>>>(counter, out);
}

// Round 4
// 157.084 us; speedup vs baseline: 1.4154x; 1.4154x over previous
//
#include <hip/hip_runtime.h>
#include <cstdint>
#include <cstddef>

#define HH 512
#define WW 512
#define BB 64
#define RPW 16            // rows per wave-strip
#define STRIPS (HH / RPW) // 32

// ws layout:
//   bits   : uint8[2][BB][HH][64]  (bit j of byte l = boundary at col 8*l+j) = 4 MB
//   counter: unsigned long long
//
// Algebra: binary masks -> class-0 and class-1 boundaries are identical
// (maxpool(1-m)-minpool(1-m) == maxpool(m)-minpool(m)), so boundary_mask = 2*b',
// b' in {0,1}; loss = 4/N * popcount(bp' XOR bg') after remove_long_lines —
// exact in integers. -inf padding == window restriction: vertical handled by
// +/-inf sentinel rows, horizontal by edge clamp (duplication harmless for max/min).

__global__ __launch_bounds__(256) void boundary_bits_kernel(
    const float* __restrict__ seg, const float* __restrict__ gt,
    uint8_t* __restrict__ bits,
    unsigned long long* __restrict__ counter)
{
    if (blockIdx.x == 0 && threadIdx.x == 0) *counter = 0ull;

    const int lane  = threadIdx.x & 63;
    const int wid   = blockIdx.x * 4 + (threadIdx.x >> 6); // 4 waves/block
    const int z     = wid >> 11;          // 2048 waves per input
    const int rem   = wid & 2047;
    const int b     = rem >> 5;
    const int strip = rem & 31;
    const int r0    = strip * RPW;

    const float* img = (z ? gt : seg) + (size_t)b * HH * WW;
    uint8_t* brow = bits + (((size_t)z * BB + b) * HH) * 64;

    float hmx[3][8], hmn[3][8];

    auto loadrow = [&](int slot, int g) {
        if (unsigned(g) < (unsigned)HH) {
            const float* p = img + (size_t)g * WW + lane * 8;
            float4 va = *(const float4*)p;
            float4 vb = *(const float4*)(p + 4);
            int sl = (lane == 0) ? 0 : lane - 1;
            int sr = (lane == 63) ? 63 : lane + 1;
            float lf = __shfl(vb.w, sl); lf = (lane == 0)  ? va.x : lf;
            float rt = __shfl(va.x, sr); rt = (lane == 63) ? vb.w : rt;
            float e[10] = {lf, va.x, va.y, va.z, va.w, vb.x, vb.y, vb.z, vb.w, rt};
            #pragma unroll
            for (int c = 0; c < 8; ++c) {
                hmx[slot][c] = fmaxf(fmaxf(e[c], e[c + 1]), e[c + 2]);
                hmn[slot][c] = fminf(fminf(e[c], e[c + 1]), e[c + 2]);
            }
        } else {
            #pragma unroll
            for (int c = 0; c < 8; ++c) { hmx[slot][c] = -1e30f; hmn[slot][c] = 1e30f; }
        }
    };

    loadrow(0, r0 - 1);
    loadrow(1, r0);
    #pragma unroll
    for (int q = 0; q < RPW; ++q) {
        const int sP = q % 3, sC = (q + 1) % 3, sN = (q + 2) % 3;
        loadrow(sN, r0 + q + 1);
        unsigned byte = 0;
        #pragma unroll
        for (int c = 0; c < 8; ++c) {
            float wmax = fmaxf(fmaxf(hmx[sP][c], hmx[sC][c]), hmx[sN][c]);
            float wmin = fminf(fminf(hmn[sP][c], hmn[sC][c]), hmn[sN][c]);
            byte |= (wmax - wmin > 0.5f) ? (1u << c) : 0u;
        }
        brow[(size_t)(r0 + q) * 64 + lane] = (uint8_t)byte;
    }
}

__global__ __launch_bounds__(512) void colmask_xor_kernel(
    const uint64_t* __restrict__ bits,
    unsigned long long* __restrict__ counter)
{
    const int w   = blockIdx.x;  // word group (cols 64w..64w+63)
    const int b   = blockIdx.y;  // batch
    const int tid = threadIdx.x; // = row (0..511)
    const int wave = tid >> 6, lane = tid & 63;

    __shared__ unsigned int part[8][64];
    __shared__ unsigned long long cmaskS[2];
    __shared__ int red[8];

    uint64_t wd[2];
    #pragma unroll
    for (int z = 0; z < 2; ++z) {
        const uint64_t* bp = bits + ((size_t)z * BB + b) * HH * 8 + (size_t)tid * 8;
        // full-row popcount (coalesced 64B/thread) -> rowhit
        uint64_t r[8];
        #pragma unroll
        for (int i = 0; i < 8; ++i) r[i] = bp[i];
        int rs = 0;
        #pragma unroll
        for (int i = 0; i < 8; ++i) rs += (int)__popcll(r[i]);
        uint64_t word = bp[w];               // this block's word (L1 hit)
        word = (rs >= 300) ? 0ull : word;    // row removal (applied BEFORE col sums)

        // per-wave column partial counts via ballot transpose: lane c keeps col c
        unsigned myp = 0;
        #pragma unroll
        for (int c = 0; c < 64; ++c) {
            unsigned long long m = __ballot((word >> c) & 1ull);
            if (lane == c) myp = (unsigned)__popcll(m);
        }
        part[wave][lane] = myp;
        __syncthreads();
        if (tid < 64) {                       // wave 0, fully active
            int s = 0;
            #pragma unroll
            for (int v = 0; v < 8; ++v) s += part[v][tid];
            unsigned long long km = __ballot(s < 300);  // keep-mask for cols 64w..
            if (tid == 0) cmaskS[z] = km;
        }
        __syncthreads();
        wd[z] = word;
    }

    uint64_t x = (wd[0] & cmaskS[0]) ^ (wd[1] & cmaskS[1]);
    int cnt = (int)__popcll(x);
    #pragma unroll
    for (int off = 32; off; off >>= 1) cnt += __shfl_down(cnt, off);
    if (lane == 0) red[wave] = cnt;
    __syncthreads();
    if (tid == 0) {
        int s = 0;
        #pragma unroll
        for (int v = 0; v < 8; ++v) s += red[v];
        atomicAdd(counter, (unsigned long long)s);
    }
}

__global__ void finalize_kernel(const unsigned long long* __restrict__ counter,
                                float* __restrict__ out)
{
    if (threadIdx.x == 0 && blockIdx.x == 0) {
        double v = (double)(*counter) * (4.0 / 16777216.0); // 4/N, N = 64*512*512
        out[0] = (float)v;
    }
}

extern "C" void kernel_launch(void* const* d_in, const int* in_sizes, int n_in,
                              void* d_out, int out_size, void* d_ws, size_t ws_size,
                              hipStream_t stream) {
    const float* seg = (const float*)d_in[0];
    const float* gt  = (const float*)d_in[1];
    float* out = (float*)d_out;

    uint8_t* ws = (uint8_t*)d_ws;
    const size_t bits_bytes = (size_t)2 * BB * HH * 64; // 4 MB
    uint8_t* bits = ws;
    unsigned long long* counter = (unsigned long long*)(ws + bits_bytes);

    // K1: 2 inputs * 64 batches * 32 strips = 4096 waves / 4 per block
    boundary_bits_kernel<<<1024, 256, 0, stream>>>(seg, gt, bits, counter);
    // K2: one block per (word-group, batch)
    dim3 g2(8, BB);
    colmask_xor_kernel<<<g2, 512, 0, stream>>>((const uint64_t*)bits, counter);
    finalize_kernel<<<1, 1, 0, stream>>>(counter, out);
}